// Round 1
// baseline (506.293 us; speedup 1.0000x reference)
//
#include <hip/hip_runtime.h>
#include <hip/hip_bf16.h>

// Sizes fixed by the reference
#define NN 4096   // node count (M and K of the big GEMMs)
#define DD 128    // feature dim
#define BATCH 4096

typedef __attribute__((ext_vector_type(8))) short bf16x8;
typedef __attribute__((ext_vector_type(4))) float f32x4;

static __device__ __forceinline__ unsigned short f2bf(float f) {
  union { float f; unsigned int u; } c; c.f = f;
  unsigned int r = c.u + 0x7FFFu + ((c.u >> 16) & 1u);  // RNE
  return (unsigned short)(r >> 16);
}

// ---------------------------------------------------------------------------
// C[M,128] += A[M,4096](f32) @ B[4096,128](f32), split-K over gridDim.y (8),
// two independent problems selected by blockIdx.z. bf16 MFMA 16x16x32.
// Tile: BM=128, BN=128, BK=64. 256 threads (4 waves, 2x2 of 64x64).
// ---------------------------------------------------------------------------
__global__ __launch_bounds__(256) void gemm_nk128(
    const float* __restrict__ A0, const float* __restrict__ A1,
    const float* __restrict__ B0, const float* __restrict__ B1,
    float* __restrict__ C0, float* __restrict__ C1)
{
  const float* A  = blockIdx.z ? A1 : A0;
  const float* Bm = blockIdx.z ? B1 : B0;
  float*       C  = blockIdx.z ? C1 : C0;

  // XOR-swizzled LDS: element (r,k) stored at r*64 + (k ^ ((r&7)<<3)).
  // Breaks the 128B-row-stride 16-way bank conflict on ds_read_b128.
  __shared__ __attribute__((aligned(16))) unsigned short sA[128 * 64];
  __shared__ __attribute__((aligned(16))) unsigned short sB[128 * 64]; // transposed: [col][k]

  const int tid  = threadIdx.x;
  const int lane = tid & 63;
  const int w    = tid >> 6;
  const int wr   = w >> 1, wc = w & 1;
  const int bm   = blockIdx.x;
  const int kc0  = blockIdx.y * 512;

  f32x4 acc[4][4];
#pragma unroll
  for (int mi = 0; mi < 4; ++mi)
#pragma unroll
    for (int ni = 0; ni < 4; ++ni)
      acc[mi][ni] = (f32x4){0.f, 0.f, 0.f, 0.f};

  for (int kt = 0; kt < 8; ++kt) {
    const int k0 = kc0 + kt * 64;

    // ---- stage A tile 128x64 (fp32 -> bf16), coalesced float4 reads ----
#pragma unroll
    for (int it = 0; it < 8; ++it) {
      int idx = it * 256 + tid;      // 0..2047 float4s
      int r   = idx >> 4;            // 16 float4 per row
      int c4  = idx & 15;
      float4 v = *(const float4*)&A[(size_t)(bm * 128 + r) * NN + k0 + c4 * 4];
      unsigned int lo = f2bf(v.x) | ((unsigned int)f2bf(v.y) << 16);
      unsigned int hi = f2bf(v.z) | ((unsigned int)f2bf(v.w) << 16);
      int off = r * 64 + ((c4 * 4) ^ ((r & 7) << 3));
      *(uint2*)&sA[off] = make_uint2(lo, hi);
    }
    // ---- stage B tile 64x128 transposed into [col][k] ----
#pragma unroll
    for (int it = 0; it < 8; ++it) {
      int idx = it * 256 + tid;      // 0..2047 float4s
      int rk  = idx >> 5;            // k row 0..63
      int c4  = idx & 31;            // col/4
      float4 v = *(const float4*)&Bm[(size_t)(k0 + rk) * DD + c4 * 4];
      int c = c4 * 4;
      sB[(c + 0) * 64 + (rk ^ (((c + 0) & 7) << 3))] = f2bf(v.x);
      sB[(c + 1) * 64 + (rk ^ (((c + 1) & 7) << 3))] = f2bf(v.y);
      sB[(c + 2) * 64 + (rk ^ (((c + 2) & 7) << 3))] = f2bf(v.z);
      sB[(c + 3) * 64 + (rk ^ (((c + 3) & 7) << 3))] = f2bf(v.w);
    }
    __syncthreads();

#pragma unroll
    for (int ks = 0; ks < 2; ++ks) {
      const int kk = ks * 32 + (lane >> 4) * 8;
      bf16x8 af[4], bfv[4];
#pragma unroll
      for (int mi = 0; mi < 4; ++mi) {
        int row = wr * 64 + mi * 16 + (lane & 15);
        af[mi] = *(const bf16x8*)&sA[row * 64 + (kk ^ ((row & 7) << 3))];
      }
#pragma unroll
      for (int ni = 0; ni < 4; ++ni) {
        int col = wc * 64 + ni * 16 + (lane & 15);
        bfv[ni] = *(const bf16x8*)&sB[col * 64 + (kk ^ ((col & 7) << 3))];
      }
#pragma unroll
      for (int mi = 0; mi < 4; ++mi)
#pragma unroll
        for (int ni = 0; ni < 4; ++ni)
          acc[mi][ni] = __builtin_amdgcn_mfma_f32_16x16x32_bf16(
              af[mi], bfv[ni], acc[mi][ni], 0, 0, 0);
    }
    __syncthreads();
  }

  // ---- split-K accumulate: atomicAdd into fp32 C ----
  // C/D layout (m89-verified): col = lane&15, row = (lane>>4)*4 + reg
  const int rbase = bm * 128 + wr * 64 + (lane >> 4) * 4;
  const int cbase = wc * 64 + (lane & 15);
#pragma unroll
  for (int mi = 0; mi < 4; ++mi)
#pragma unroll
    for (int ni = 0; ni < 4; ++ni)
#pragma unroll
      for (int r = 0; r < 4; ++r)
        atomicAdd(&C[(size_t)(rbase + mi * 16 + r) * DD + cbase + ni * 16],
                  acc[mi][ni][r]);
}

// ---------------------------------------------------------------------------
// rowsum of the two review matrices: rs[mat*4096 + row]
// ---------------------------------------------------------------------------
__global__ __launch_bounds__(256) void rowsum_kernel(
    const float* __restrict__ revA, const float* __restrict__ revB,
    float* __restrict__ rs)
{
  int bid = blockIdx.x;            // 0..8191
  int mat = bid >> 12;
  int row = bid & 4095;
  const float* src = (mat ? revB : revA) + (size_t)row * NN;
  int tid = threadIdx.x;
  float s = 0.f;
#pragma unroll
  for (int it = 0; it < 4; ++it) {
    float4 v = *(const float4*)&src[(it * 256 + tid) * 4];
    s += v.x + v.y + v.z + v.w;
  }
#pragma unroll
  for (int off = 32; off; off >>= 1) s += __shfl_down(s, off, 64);
  __shared__ float red[4];
  if ((tid & 63) == 0) red[tid >> 6] = s;
  __syncthreads();
  if (tid == 0) rs[mat * 4096 + row] = red[0] + red[1] + red[2] + red[3];
}

// ---------------------------------------------------------------------------
// colsum of Wr_A / Wr_B: cs[mat*128 + d]  (cs pre-zeroed)
// ---------------------------------------------------------------------------
__global__ __launch_bounds__(256) void colsum_kernel(
    const float* __restrict__ WrA, const float* __restrict__ WrB,
    float* __restrict__ cs)
{
  const float* Wm = blockIdx.y ? WrB : WrA;
  int d  = threadIdx.x & 127;
  int h  = threadIdx.x >> 7;
  int r0 = blockIdx.x * 256 + h * 128;
  float s = 0.f;
  for (int r = r0; r < r0 + 128; ++r) s += Wm[(size_t)r * DD + d];
  atomicAdd(&cs[blockIdx.y * 128 + d], s);
}

// ---------------------------------------------------------------------------
// gather + domain mix; relu applied lazily here (GEMM outputs are pre-act)
// vX[n,d] = relu(rowsum_X[n] * colsum(Wr_X)[d])
// ---------------------------------------------------------------------------
__global__ __launch_bounds__(256) void gather_mix(
    const float* __restrict__ preA, const float* __restrict__ preB,
    const float* __restrict__ rs, const float* __restrict__ cs,
    const float* __restrict__ attA, const float* __restrict__ attB,
    const int* __restrict__ u, const int* __restrict__ ii,
    const int* __restrict__ domainp,
    float* __restrict__ userv, float* __restrict__ itemv)
{
  int tid = threadIdx.x;
  int d = tid & 127;
  int b = blockIdx.x * 2 + (tid >> 7);
  int dom = domainp[0];
  int ub = u[b], ib = ii[b];
  float pA = fmaxf(preA[(size_t)ub * DD + d], 0.f);
  float pB = fmaxf(preB[(size_t)ub * DD + d], 0.f);
  float va = fmaxf(rs[ub] * cs[d], 0.f);
  float vb = fmaxf(rs[4096 + ub] * cs[128 + d], 0.f);
  float uA = pA + va, uB = pB + vb;
  float wgt = dom ? attB[(size_t)ub * DD + d] : attA[(size_t)ub * DD + d];
  float user = dom ? (uB * wgt + uA * (1.f - wgt))
                   : (uA * wgt + uB * (1.f - wgt));
  const float* preI = dom ? preB : preA;
  float item = fmaxf(preI[(size_t)ib * DD + d], 0.f);
  userv[(size_t)b * DD + d] = user;
  itemv[(size_t)b * DD + d] = item;
}

// ---------------------------------------------------------------------------
// out[b,:] = (relu?)(x[b,:] @ W + bias).  W (128x128) staged in LDS (64KB).
// 256 threads = 16 rows x 16 col-groups(8 cols). grid = 4096/16 = 256.
// ---------------------------------------------------------------------------
__global__ __launch_bounds__(256) void mlp_stage(
    const float* __restrict__ x, const float* __restrict__ W,
    const float* __restrict__ bias, float* __restrict__ out, int do_relu)
{
  __shared__ float sW[128 * 128];
  int tid = threadIdx.x;
#pragma unroll
  for (int it = 0; it < 16; ++it) {
    int idx = (it * 256 + tid) * 4;
    *(float4*)&sW[idx] = *(const float4*)&W[idx];
  }
  __syncthreads();

  int r  = blockIdx.x * 16 + (tid >> 4);
  int cg = (tid & 15) * 8;
  const float* xrow = x + (size_t)r * DD;
  float4 a0 = {0, 0, 0, 0}, a1 = {0, 0, 0, 0};
  for (int k4 = 0; k4 < 32; ++k4) {
    float4 xv = *(const float4*)&xrow[k4 * 4];
    float xs[4] = {xv.x, xv.y, xv.z, xv.w};
#pragma unroll
    for (int kk = 0; kk < 4; ++kk) {
      int k = k4 * 4 + kk;
      float4 w0 = *(const float4*)&sW[k * 128 + cg];
      float4 w1 = *(const float4*)&sW[k * 128 + cg + 4];
      a0.x += xs[kk] * w0.x; a0.y += xs[kk] * w0.y;
      a0.z += xs[kk] * w0.z; a0.w += xs[kk] * w0.w;
      a1.x += xs[kk] * w1.x; a1.y += xs[kk] * w1.y;
      a1.z += xs[kk] * w1.z; a1.w += xs[kk] * w1.w;
    }
  }
  float4 b0 = *(const float4*)&bias[cg];
  float4 b1 = *(const float4*)&bias[cg + 4];
  a0.x += b0.x; a0.y += b0.y; a0.z += b0.z; a0.w += b0.w;
  a1.x += b1.x; a1.y += b1.y; a1.z += b1.z; a1.w += b1.w;
  if (do_relu) {
    a0.x = fmaxf(a0.x, 0.f); a0.y = fmaxf(a0.y, 0.f);
    a0.z = fmaxf(a0.z, 0.f); a0.w = fmaxf(a0.w, 0.f);
    a1.x = fmaxf(a1.x, 0.f); a1.y = fmaxf(a1.y, 0.f);
    a1.z = fmaxf(a1.z, 0.f); a1.w = fmaxf(a1.w, 0.f);
  }
  *(float4*)&out[(size_t)r * DD + cg]     = a0;
  *(float4*)&out[(size_t)r * DD + cg + 4] = a1;
}

// ---------------------------------------------------------------------------
extern "C" void kernel_launch(void* const* d_in, const int* in_sizes, int n_in,
                              void* d_out, int out_size, void* d_ws, size_t ws_size,
                              hipStream_t stream)
{
  const float* ratingA = (const float*)d_in[0];
  const float* ratingB = (const float*)d_in[1];
  const float* reviewA = (const float*)d_in[2];
  const float* reviewB = (const float*)d_in[3];
  const float* WgA = (const float*)d_in[4];
  const float* WgB = (const float*)d_in[5];
  const float* WrA = (const float*)d_in[6];
  const float* WrB = (const float*)d_in[7];
  const float* attA = (const float*)d_in[8];
  const float* attB = (const float*)d_in[9];
  const float* uW1 = (const float*)d_in[10];
  const float* ub1 = (const float*)d_in[11];
  const float* uW2 = (const float*)d_in[12];
  const float* ub2 = (const float*)d_in[13];
  const float* iW1 = (const float*)d_in[14];
  const float* ib1 = (const float*)d_in[15];
  const float* iW2 = (const float*)d_in[16];
  const float* ib2 = (const float*)d_in[17];
  const int* u   = (const int*)d_in[18];
  const int* ii  = (const int*)d_in[19];
  const int* dom = (const int*)d_in[20];
  float* out = (float*)d_out;

  const size_t ND = (size_t)NN * DD;        // 524288
  float* ws   = (float*)d_ws;
  float* T_A  = ws;
  float* T_B  = ws + ND;
  float* preA = ws + 2 * ND;
  float* preB = ws + 3 * ND;
  float* cs   = ws + 4 * ND;                // 256
  float* rs   = cs + 256;                   // 8192
  float* userv = rs + 8192;
  float* itemv = userv + ND;
  float* hidU  = itemv + ND;
  float* hidI  = hidU + ND;

  // zero split-K accumulators + colsum buffers
  hipMemsetAsync(d_ws, 0, (4 * ND + 256) * sizeof(float), stream);

  rowsum_kernel<<<8192, 256, 0, stream>>>(reviewA, reviewB, rs);
  colsum_kernel<<<dim3(16, 2), 256, 0, stream>>>(WrA, WrB, cs);

  // T = rating @ Wg
  gemm_nk128<<<dim3(32, 8, 2), 256, 0, stream>>>(ratingA, ratingB, WgA, WgB, T_A, T_B);
  // pre = rating @ T   (relu deferred to gather)
  gemm_nk128<<<dim3(32, 8, 2), 256, 0, stream>>>(ratingA, ratingB, T_A, T_B, preA, preB);

  gather_mix<<<2048, 256, 0, stream>>>(preA, preB, rs, cs, attA, attB, u, ii, dom,
                                       userv, itemv);

  mlp_stage<<<256, 256, 0, stream>>>(userv, uW1, ub1, hidU, 1);
  mlp_stage<<<256, 256, 0, stream>>>(hidU, uW2, ub2, out, 0);
  mlp_stage<<<256, 256, 0, stream>>>(itemv, iW1, ib1, hidI, 1);
  mlp_stage<<<256, 256, 0, stream>>>(hidI, iW2, ib2, out + (size_t)BATCH * DD, 0);
}

// Round 3
// 465.551 us; speedup vs baseline: 1.0875x; 1.0875x over previous
//
#include <hip/hip_runtime.h>
#include <hip/hip_bf16.h>
#include <stdint.h>

#define NN 4096   // node count (K and node-dim of big GEMMs)
#define DD 128    // feature dim
#define BATCH 4096

typedef __attribute__((ext_vector_type(8))) short bf16x8;
typedef __attribute__((ext_vector_type(4))) float f32x4;

static __device__ __forceinline__ unsigned short f2bf(float f) {
  union { float f; unsigned int u; } c; c.f = f;
  unsigned int r = c.u + 0x7FFFu + ((c.u >> 16) & 1u);  // RNE
  return (unsigned short)(r >> 16);
}

typedef __attribute__((address_space(3))) void lds_t;
typedef __attribute__((address_space(1))) void gm_t;
static __device__ __forceinline__ void gload16(const void* g, void* l) {
  __builtin_amdgcn_global_load_lds((const gm_t*)g, (lds_t*)l, 16, 0, 0);
}

// ---------------------------------------------------------------------------
// prep: one dispatch doing 4 independent streaming jobs (block-range switch)
//  [0,8192)      rowsum of review matrices -> rs[2][4096]
//  [8192,10240)  rating fp32 -> bf16 copy (row-major, same layout)
//  [10240,10752) colsum of Wr -> cs[2][128]   (cs pre-zeroed)
//  [10752,10880) Wg [4096][128] f32 -> WgT bf16 [128][4096]
// ---------------------------------------------------------------------------
__global__ __launch_bounds__(256) void prep_kernel(
    const float* __restrict__ ratingA, const float* __restrict__ ratingB,
    const float* __restrict__ reviewA, const float* __restrict__ reviewB,
    const float* __restrict__ WgA, const float* __restrict__ WgB,
    const float* __restrict__ WrA, const float* __restrict__ WrB,
    unsigned short* __restrict__ rating_bf,   // [2][4096*4096]
    unsigned short* __restrict__ WgT,         // [2][128*4096]
    float* __restrict__ rs,                   // [2][4096]
    float* __restrict__ cs)                   // [2][128]
{
  __shared__ float smem[64 * 129];
  const int tid = threadIdx.x;
  int bid = blockIdx.x;

  if (bid < 8192) {                    // ---- rowsum ----
    int mat = bid >> 12, row = bid & 4095;
    const float* src = (mat ? reviewB : reviewA) + (size_t)row * NN;
    float s = 0.f;
#pragma unroll
    for (int it = 0; it < 4; ++it) {
      float4 v = *(const float4*)&src[(it * 256 + tid) * 4];
      s += v.x + v.y + v.z + v.w;
    }
#pragma unroll
    for (int off = 32; off; off >>= 1) s += __shfl_down(s, off, 64);
    if ((tid & 63) == 0) smem[tid >> 6] = s;
    __syncthreads();
    if (tid == 0) rs[(size_t)mat * 4096 + row] = smem[0] + smem[1] + smem[2] + smem[3];
    return;
  }
  bid -= 8192;
  if (bid < 2048) {                    // ---- rating f32 -> bf16 ----
    int mat = bid >> 10;
    const float* src = mat ? ratingB : ratingA;
    unsigned short* dst = rating_bf + (size_t)mat * NN * NN;
    size_t base = (size_t)(bid & 1023) * 16384;
#pragma unroll
    for (int it = 0; it < 16; ++it) {
      size_t idx = base + (size_t)(it * 256 + tid) * 4;
      float4 v = *(const float4*)&src[idx];
      ushort4 o = { f2bf(v.x), f2bf(v.y), f2bf(v.z), f2bf(v.w) };
      *(ushort4*)&dst[idx] = o;
    }
    return;
  }
  bid -= 2048;
  if (bid < 512) {                     // ---- colsum of Wr ----
    int mat = bid >> 8;
    int r0 = (bid & 255) * 16;
    const float* Wm = mat ? WrB : WrA;
    int c = tid & 127, h = tid >> 7;
    float s = 0.f;
#pragma unroll
    for (int j = 0; j < 8; ++j)
      s += Wm[(size_t)(r0 + h * 8 + j) * DD + c];
    smem[tid] = s;
    __syncthreads();
    if (h == 0) atomicAdd(&cs[mat * DD + c], smem[c] + smem[128 + c]);
    return;
  }
  bid -= 512;
  {                                    // ---- transpose Wg -> WgT bf16 ----
    int mat = bid >> 6;
    int r0 = (bid & 63) * 64;
    const float* Wm = mat ? WgB : WgA;
    unsigned short* dst = WgT + (size_t)mat * DD * NN;
#pragma unroll
    for (int it = 0; it < 8; ++it) {
      int idx = it * 256 + tid;        // 2048 float4s = 64 rows x 128 cols
      int r = idx >> 5, c4 = idx & 31;
      float4 v = *(const float4*)&Wm[(size_t)(r0 + r) * DD + c4 * 4];
      smem[r * 129 + c4 * 4 + 0] = v.x;
      smem[r * 129 + c4 * 4 + 1] = v.y;
      smem[r * 129 + c4 * 4 + 2] = v.z;
      smem[r * 129 + c4 * 4 + 3] = v.w;
    }
    __syncthreads();
    int n = tid >> 1, mh = (tid & 1) * 32;
    unsigned int* dstu = (unsigned int*)&dst[(size_t)n * NN + r0 + mh];
#pragma unroll
    for (int j = 0; j < 16; ++j) {
      unsigned int lo = f2bf(smem[(mh + 2 * j) * 129 + n]);
      unsigned int hi = f2bf(smem[(mh + 2 * j + 1) * 129 + n]);
      dstu[j] = lo | (hi << 16);
    }
  }
}

// ---------------------------------------------------------------------------
// D'[n(128)][m(4096)] += sum_k X[n][k] * Y[m][k]
// X = small matrix transposed (bf16 [128][4096]), Y = rating bf16 [4096][4096].
// Both operands contiguous along k -> global_load_lds(16B) with pre-swizzled
// source addresses (LDS slot (r, w) holds element k0 + (w ^ ((r&7)<<3))).
// BM(n)=128, BN(m)=128, BK=64, split-K=8, 4 waves, double-buffered, vmcnt(8).
// TRANSPOSED_OUT=1: O[n*4096+m] (for T'); =0: O[m*128+n] (for pre).
// ---------------------------------------------------------------------------
template<int TRANSPOSED_OUT>
__global__ __launch_bounds__(256) void gemm_tall(
    const unsigned short* __restrict__ Xg0, const unsigned short* __restrict__ Xg1,
    const unsigned short* __restrict__ Yg0, const unsigned short* __restrict__ Yg1,
    float* __restrict__ O0, float* __restrict__ O1)
{
  __shared__ __attribute__((aligned(16))) unsigned short sX[2][128 * 64];
  __shared__ __attribute__((aligned(16))) unsigned short sY[2][128 * 64];

  const int tid  = threadIdx.x;
  const int lane = tid & 63;
  const int bm   = blockIdx.x;       // m-block
  const int kz   = blockIdx.y;       // split-K
  const unsigned short* Xg = blockIdx.z ? Xg1 : Xg0;
  const unsigned short* Yg = blockIdx.z ? Yg1 : Yg0;
  float* Og = blockIdx.z ? O1 : O0;
  const int w = tid >> 6, wr = w >> 1, wc = w & 1;

  const int sr8 = tid >> 3;          // staging: row within 32-row group
  const int kk8 = (tid & 7) * 8;     // staging: 8-aligned k slot

  f32x4 acc[4][4];
#pragma unroll
  for (int i = 0; i < 4; ++i)
#pragma unroll
    for (int j = 0; j < 4; ++j)
      acc[i][j] = (f32x4){0.f, 0.f, 0.f, 0.f};

  auto STAGE = [&](int buf, int kt) {
    const int k0 = kz * 512 + kt * 64;
#pragma unroll
    for (int it = 0; it < 4; ++it) {
      int r = it * 32 + sr8;
      int o = r * 64 + kk8;
      int ks = k0 + (kk8 ^ ((r & 7) << 3));   // inverse-swizzled source
      gload16(Xg + (size_t)r * NN + ks, &sX[buf][o]);
      gload16(Yg + (size_t)(bm * 128 + r) * NN + ks, &sY[buf][o]);
    }
  };

  STAGE(0, 0);
  int cur = 0;
  for (int kt = 0; kt < 8; ++kt) {
    if (kt < 7) {
      STAGE(cur ^ 1, kt + 1);
      asm volatile("s_waitcnt vmcnt(8)" ::: "memory");   // cur done, next in flight
    } else {
      asm volatile("s_waitcnt vmcnt(0)" ::: "memory");
    }
    __builtin_amdgcn_s_barrier();
    __builtin_amdgcn_sched_barrier(0);
#pragma unroll
    for (int ks = 0; ks < 2; ++ks) {
      const int kk = ks * 32 + (lane >> 4) * 8;
      bf16x8 av[4], bv[4];
#pragma unroll
      for (int i = 0; i < 4; ++i) {
        int rn = wr * 64 + i * 16 + (lane & 15);
        av[i] = *(const bf16x8*)&sX[cur][rn * 64 + (kk ^ ((rn & 7) << 3))];
        int rm = wc * 64 + i * 16 + (lane & 15);
        bv[i] = *(const bf16x8*)&sY[cur][rm * 64 + (kk ^ ((rm & 7) << 3))];
      }
#pragma unroll
      for (int i = 0; i < 4; ++i)
#pragma unroll
        for (int j = 0; j < 4; ++j)
          acc[i][j] = __builtin_amdgcn_mfma_f32_16x16x32_bf16(av[i], bv[j], acc[i][j], 0, 0, 0);
    }
    __builtin_amdgcn_s_barrier();
    cur ^= 1;
  }

  // split-K accumulate (C/D: col=lane&15 -> m, row=(lane>>4)*4+reg -> n)
  const int mlo = bm * 128 + wc * 64 + (lane & 15);
  const int nlo = wr * 64 + (lane >> 4) * 4;
#pragma unroll
  for (int i = 0; i < 4; ++i)
#pragma unroll
    for (int j = 0; j < 4; ++j)
#pragma unroll
      for (int r = 0; r < 4; ++r) {
        int n = nlo + i * 16 + r;
        int m = mlo + j * 16;
        if (TRANSPOSED_OUT)
          atomicAdd(&Og[(size_t)n * NN + m], acc[i][j][r]);
        else
          atomicAdd(&Og[(size_t)m * DD + n], acc[i][j][r]);
      }
}

// ---------------------------------------------------------------------------
// T' fp32 [2][128][4096] -> Tt bf16 same layout
// ---------------------------------------------------------------------------
__global__ __launch_bounds__(256) void convT_kernel(
    const float* __restrict__ Tp, unsigned short* __restrict__ Tt)
{
  size_t idx = ((size_t)blockIdx.x * 256 + threadIdx.x) * 8;
  float4 a = *(const float4*)&Tp[idx];
  float4 b = *(const float4*)&Tp[idx + 4];
  ushort4 o1 = { f2bf(a.x), f2bf(a.y), f2bf(a.z), f2bf(a.w) };
  ushort4 o2 = { f2bf(b.x), f2bf(b.y), f2bf(b.z), f2bf(b.w) };
  *(ushort4*)&Tt[idx] = o1;
  *(ushort4*)&Tt[idx + 4] = o2;
}

// ---------------------------------------------------------------------------
// tail: gather + domain mix + 2-layer MLP, one block = 16 batch rows.
// blockIdx.y: 0 = user path, 1 = item path. W staged in LDS (reused buffer).
// ---------------------------------------------------------------------------
#define FMA4(acc4, sc, wv) { (acc4).x += (sc) * (wv).x; (acc4).y += (sc) * (wv).y; \
                             (acc4).z += (sc) * (wv).z; (acc4).w += (sc) * (wv).w; }

__global__ __launch_bounds__(256) void tail_kernel(
    const float* __restrict__ preA, const float* __restrict__ preB,  // [4096][128]
    const float* __restrict__ rs, const float* __restrict__ cs,
    const float* __restrict__ attA, const float* __restrict__ attB,
    const int* __restrict__ u, const int* __restrict__ ii, const int* __restrict__ domp,
    const float* __restrict__ uW1, const float* __restrict__ ub1,
    const float* __restrict__ uW2, const float* __restrict__ ub2,
    const float* __restrict__ iW1, const float* __restrict__ ib1,
    const float* __restrict__ iW2, const float* __restrict__ ib2,
    float* __restrict__ out)
{
  __shared__ float sW[128 * 128];
  __shared__ float sX[16 * 128];
  __shared__ float sH[16 * 128];
  const int tid = threadIdx.x;
  const int path = blockIdx.y;
  const int b0 = blockIdx.x * 16;
  const int dom = domp[0];

  {  // gather + mix into sX
    int d = tid & 127, rr = tid >> 7;
#pragma unroll
    for (int it = 0; it < 8; ++it) {
      int rloc = it * 2 + rr;
      int b = b0 + rloc;
      float xv;
      if (path == 0) {
        int ub = u[b];
        float pA = fmaxf(preA[(size_t)ub * DD + d], 0.f);
        float pB = fmaxf(preB[(size_t)ub * DD + d], 0.f);
        float va = fmaxf(rs[ub] * cs[d], 0.f);
        float vb = fmaxf(rs[4096 + ub] * cs[128 + d], 0.f);
        float uA = pA + va, uB = pB + vb;
        float wgt = dom ? attB[(size_t)ub * DD + d] : attA[(size_t)ub * DD + d];
        xv = dom ? (uB * wgt + uA * (1.f - wgt)) : (uA * wgt + uB * (1.f - wgt));
      } else {
        int ib = ii[b];
        xv = fmaxf((dom ? preB : preA)[(size_t)ib * DD + d], 0.f);
      }
      sX[rloc * 128 + d] = xv;
    }
  }
  const float* W1 = path ? iW1 : uW1;
  const float* B1 = path ? ib1 : ub1;
  const float* W2 = path ? iW2 : uW2;
  const float* B2 = path ? ib2 : ub2;
#pragma unroll
  for (int it = 0; it < 16; ++it) {
    int idx = (it * 256 + tid) * 4;
    *(float4*)&sW[idx] = *(const float4*)&W1[idx];
  }
  __syncthreads();

  const int rl = tid >> 4, cg = (tid & 15) * 8;
  {  // layer 1 + relu -> sH
    float4 a0 = {0, 0, 0, 0}, a1 = {0, 0, 0, 0};
    const float* xr = &sX[rl * 128];
    for (int k = 0; k < 128; ++k) {
      float xk = xr[k];
      float4 w0 = *(const float4*)&sW[k * 128 + cg];
      float4 w1 = *(const float4*)&sW[k * 128 + cg + 4];
      FMA4(a0, xk, w0); FMA4(a1, xk, w1);
    }
    float4 c0 = *(const float4*)&B1[cg];
    float4 c1 = *(const float4*)&B1[cg + 4];
    a0.x = fmaxf(a0.x + c0.x, 0.f); a0.y = fmaxf(a0.y + c0.y, 0.f);
    a0.z = fmaxf(a0.z + c0.z, 0.f); a0.w = fmaxf(a0.w + c0.w, 0.f);
    a1.x = fmaxf(a1.x + c1.x, 0.f); a1.y = fmaxf(a1.y + c1.y, 0.f);
    a1.z = fmaxf(a1.z + c1.z, 0.f); a1.w = fmaxf(a1.w + c1.w, 0.f);
    *(float4*)&sH[rl * 128 + cg] = a0;
    *(float4*)&sH[rl * 128 + cg + 4] = a1;
  }
  __syncthreads();
#pragma unroll
  for (int it = 0; it < 16; ++it) {     // overwrite sW with W2
    int idx = (it * 256 + tid) * 4;
    *(float4*)&sW[idx] = *(const float4*)&W2[idx];
  }
  __syncthreads();
  {  // layer 2 -> out
    float4 a0 = {0, 0, 0, 0}, a1 = {0, 0, 0, 0};
    const float* hr = &sH[rl * 128];
    for (int k = 0; k < 128; ++k) {
      float hk = hr[k];
      float4 w0 = *(const float4*)&sW[k * 128 + cg];
      float4 w1 = *(const float4*)&sW[k * 128 + cg + 4];
      FMA4(a0, hk, w0); FMA4(a1, hk, w1);
    }
    float4 c0 = *(const float4*)&B2[cg];
    float4 c1 = *(const float4*)&B2[cg + 4];
    a0.x += c0.x; a0.y += c0.y; a0.z += c0.z; a0.w += c0.w;
    a1.x += c1.x; a1.y += c1.y; a1.z += c1.z; a1.w += c1.w;
    size_t row = (size_t)path * BATCH + b0 + rl;
    *(float4*)&out[row * DD + cg] = a0;
    *(float4*)&out[row * DD + cg + 4] = a1;
  }
}

// ---------------------------------------------------------------------------
extern "C" void kernel_launch(void* const* d_in, const int* in_sizes, int n_in,
                              void* d_out, int out_size, void* d_ws, size_t ws_size,
                              hipStream_t stream)
{
  const float* ratingA = (const float*)d_in[0];
  const float* ratingB = (const float*)d_in[1];
  const float* reviewA = (const float*)d_in[2];
  const float* reviewB = (const float*)d_in[3];
  const float* WgA = (const float*)d_in[4];
  const float* WgB = (const float*)d_in[5];
  const float* WrA = (const float*)d_in[6];
  const float* WrB = (const float*)d_in[7];
  const float* attA = (const float*)d_in[8];
  const float* attB = (const float*)d_in[9];
  const float* uW1 = (const float*)d_in[10];
  const float* ub1 = (const float*)d_in[11];
  const float* uW2 = (const float*)d_in[12];
  const float* ub2 = (const float*)d_in[13];
  const float* iW1 = (const float*)d_in[14];
  const float* ib1 = (const float*)d_in[15];
  const float* iW2 = (const float*)d_in[16];
  const float* ib2 = (const float*)d_in[17];
  const int* u   = (const int*)d_in[18];
  const int* ii  = (const int*)d_in[19];
  const int* dom = (const int*)d_in[20];
  float* out = (float*)d_out;

  const size_t ND = (size_t)NN * DD;            // 524288
  // workspace layout (76 MB)
  unsigned short* rating_bf = (unsigned short*)d_ws;             // 64 MB
  unsigned short* WgT = rating_bf + (size_t)2 * NN * NN;         //  2 MB
  unsigned short* Tt  = WgT + 2 * ND;                            //  2 MB
  float* Tp  = (float*)(Tt + 2 * ND);                            //  4 MB  [2][128][4096]
  float* pre = Tp + 2 * ND;                                      //  4 MB  [2][4096][128]
  float* cs  = pre + 2 * ND;                                     //  1 KB
  float* rs  = cs + 256;                                         // 32 KB

  // zero the atomic accumulators (Tp, pre) + cs — contiguous region
  hipMemsetAsync(Tp, 0, (4 * ND + 256) * sizeof(float), stream);

  prep_kernel<<<10880, 256, 0, stream>>>(ratingA, ratingB, reviewA, reviewB,
                                         WgA, WgB, WrA, WrB,
                                         rating_bf, WgT, rs, cs);

  // T'[d][i] = sum_j Wg[j][d] * rating[i][j]   (transposed output)
  gemm_tall<1><<<dim3(32, 8, 2), 256, 0, stream>>>(
      WgT, WgT + ND, rating_bf, rating_bf + (size_t)NN * NN, Tp, Tp + ND);

  convT_kernel<<<512, 256, 0, stream>>>(Tp, Tt);

  // pre[i][d] = sum_j Tt[d][j] * rating[i][j]  (node-major output)
  gemm_tall<0><<<dim3(32, 8, 2), 256, 0, stream>>>(
      Tt, Tt + ND, rating_bf, rating_bf + (size_t)NN * NN, pre, pre + ND);

  tail_kernel<<<dim3(256, 2), 256, 0, stream>>>(
      pre, pre + ND, rs, cs, attA, attB, u, ii, dom,
      uW1, ub1, uW2, ub2, iW1, ib1, iW2, ib2, out);
}

// Round 4
// 359.220 us; speedup vs baseline: 1.4094x; 1.2960x over previous
//
#include <hip/hip_runtime.h>
#include <hip/hip_bf16.h>
#include <stdint.h>

#define NN 4096   // node count (K and node-dim of big GEMMs)
#define DD 128    // feature dim
#define BATCH 4096

typedef __attribute__((ext_vector_type(8))) short bf16x8;
typedef __attribute__((ext_vector_type(4))) float f32x4;

static __device__ __forceinline__ unsigned short f2bf(float f) {
  union { float f; unsigned int u; } c; c.f = f;
  unsigned int r = c.u + 0x7FFFu + ((c.u >> 16) & 1u);  // RNE
  return (unsigned short)(r >> 16);
}

typedef __attribute__((address_space(3))) void lds_t;
typedef __attribute__((address_space(1))) void gm_t;
static __device__ __forceinline__ void gload16(const void* g, void* l) {
  __builtin_amdgcn_global_load_lds((const gm_t*)g, (lds_t*)l, 16, 0, 0);
}

// ---------------------------------------------------------------------------
// prep: one dispatch doing 4 independent streaming jobs (block-range switch)
//  [0,8192)      rowsum of review matrices -> rs[2][4096]
//  [8192,10240)  rating fp32 -> bf16 copy (row-major, same layout)
//  [10240,10752) colsum of Wr -> cs[2][128]   (cs pre-zeroed)
//  [10752,10880) Wg [4096][128] f32 -> WgT bf16 [128][4096]
// ---------------------------------------------------------------------------
__global__ __launch_bounds__(256) void prep_kernel(
    const float* __restrict__ ratingA, const float* __restrict__ ratingB,
    const float* __restrict__ reviewA, const float* __restrict__ reviewB,
    const float* __restrict__ WgA, const float* __restrict__ WgB,
    const float* __restrict__ WrA, const float* __restrict__ WrB,
    unsigned short* __restrict__ rating_bf,   // [2][4096*4096]
    unsigned short* __restrict__ WgT,         // [2][128*4096]
    float* __restrict__ rs,                   // [2][4096]
    float* __restrict__ cs)                   // [2][128]
{
  __shared__ float smem[64 * 129];
  const int tid = threadIdx.x;
  int bid = blockIdx.x;

  if (bid < 8192) {                    // ---- rowsum ----
    int mat = bid >> 12, row = bid & 4095;
    const float* src = (mat ? reviewB : reviewA) + (size_t)row * NN;
    float s = 0.f;
#pragma unroll
    for (int it = 0; it < 4; ++it) {
      float4 v = *(const float4*)&src[(it * 256 + tid) * 4];
      s += v.x + v.y + v.z + v.w;
    }
#pragma unroll
    for (int off = 32; off; off >>= 1) s += __shfl_down(s, off, 64);
    if ((tid & 63) == 0) smem[tid >> 6] = s;
    __syncthreads();
    if (tid == 0) rs[(size_t)mat * 4096 + row] = smem[0] + smem[1] + smem[2] + smem[3];
    return;
  }
  bid -= 8192;
  if (bid < 2048) {                    // ---- rating f32 -> bf16 ----
    int mat = bid >> 10;
    const float* src = mat ? ratingB : ratingA;
    unsigned short* dst = rating_bf + (size_t)mat * NN * NN;
    size_t base = (size_t)(bid & 1023) * 16384;
#pragma unroll
    for (int it = 0; it < 16; ++it) {
      size_t idx = base + (size_t)(it * 256 + tid) * 4;
      float4 v = *(const float4*)&src[idx];
      ushort4 o = { f2bf(v.x), f2bf(v.y), f2bf(v.z), f2bf(v.w) };
      *(ushort4*)&dst[idx] = o;
    }
    return;
  }
  bid -= 2048;
  if (bid < 512) {                     // ---- colsum of Wr ----
    int mat = bid >> 8;
    int r0 = (bid & 255) * 16;
    const float* Wm = mat ? WrB : WrA;
    int c = tid & 127, h = tid >> 7;
    float s = 0.f;
#pragma unroll
    for (int j = 0; j < 8; ++j)
      s += Wm[(size_t)(r0 + h * 8 + j) * DD + c];
    smem[tid] = s;
    __syncthreads();
    if (h == 0) atomicAdd(&cs[mat * DD + c], smem[c] + smem[128 + c]);
    return;
  }
  bid -= 512;
  {                                    // ---- transpose Wg -> WgT bf16 ----
    int mat = bid >> 6;
    int r0 = (bid & 63) * 64;
    const float* Wm = mat ? WgB : WgA;
    unsigned short* dst = WgT + (size_t)mat * DD * NN;
#pragma unroll
    for (int it = 0; it < 8; ++it) {
      int idx = it * 256 + tid;        // 2048 float4s = 64 rows x 128 cols
      int r = idx >> 5, c4 = idx & 31;
      float4 v = *(const float4*)&Wm[(size_t)(r0 + r) * DD + c4 * 4];
      smem[r * 129 + c4 * 4 + 0] = v.x;
      smem[r * 129 + c4 * 4 + 1] = v.y;
      smem[r * 129 + c4 * 4 + 2] = v.z;
      smem[r * 129 + c4 * 4 + 3] = v.w;
    }
    __syncthreads();
    int n = tid >> 1, mh = (tid & 1) * 32;
    unsigned int* dstu = (unsigned int*)&dst[(size_t)n * NN + r0 + mh];
#pragma unroll
    for (int j = 0; j < 16; ++j) {
      unsigned int lo = f2bf(smem[(mh + 2 * j) * 129 + n]);
      unsigned int hi = f2bf(smem[(mh + 2 * j + 1) * 129 + n]);
      dstu[j] = lo | (hi << 16);
    }
  }
}

// ---------------------------------------------------------------------------
// Split-K GEMM, NO atomics: each block stores its 128x128 fp32 partial tile
// to Ppart[z][kz][...]. X = small matrix bf16 [128][4096] (k-contiguous),
// Y = rating bf16 [4096][4096]. Both staged via global_load_lds(16B) with
// pre-swizzled source (LDS slot (r,w) holds k0 + (w ^ ((r&7)<<3))).
// BM=128, BN(n)=128, BK=64, split-K=8, 4 waves, double-buffered, vmcnt(8).
// SWAP=0 (GEMM1): A=X, B=Y -> tile [n(128)][m(128)] stored m-contiguous into
//                 Ppart layout [128][4096] (n-major).
// SWAP=1 (GEMM2): A=Y, B=X -> tile [m(128)][n(128)] stored n-contiguous into
//                 Ppart layout [4096][128] (m-major).
// ---------------------------------------------------------------------------
template<int SWAP>
__global__ __launch_bounds__(256) void gemm_tall(
    const unsigned short* __restrict__ Xg0, const unsigned short* __restrict__ Xg1,
    const unsigned short* __restrict__ Yg0, const unsigned short* __restrict__ Yg1,
    float* __restrict__ Ppart)   // [2][8][524288]
{
  __shared__ __attribute__((aligned(16))) unsigned short sX[2][128 * 64];
  __shared__ __attribute__((aligned(16))) unsigned short sY[2][128 * 64];

  const int tid  = threadIdx.x;
  const int lane = tid & 63;
  const int bm   = blockIdx.x;       // m-block
  const int kz   = blockIdx.y;       // split-K index
  const int z    = blockIdx.z;       // domain
  const unsigned short* Xg = z ? Xg1 : Xg0;
  const unsigned short* Yg = z ? Yg1 : Yg0;
  const int w = tid >> 6, wr = w >> 1, wc = w & 1;

  const int sr8 = tid >> 3;          // staging row within 32-row group
  const int kk8 = (tid & 7) * 8;     // staging 8-aligned k slot

  f32x4 acc[4][4];
#pragma unroll
  for (int i = 0; i < 4; ++i)
#pragma unroll
    for (int j = 0; j < 4; ++j)
      acc[i][j] = (f32x4){0.f, 0.f, 0.f, 0.f};

  auto STAGE = [&](int buf, int kt) {
    const int k0 = kz * 512 + kt * 64;
#pragma unroll
    for (int it = 0; it < 4; ++it) {
      int r = it * 32 + sr8;
      int o = r * 64 + kk8;
      int ks = k0 + (kk8 ^ ((r & 7) << 3));   // inverse-swizzled source
      gload16(Xg + (size_t)r * NN + ks, &sX[buf][o]);
      gload16(Yg + (size_t)(bm * 128 + r) * NN + ks, &sY[buf][o]);
    }
  };

  STAGE(0, 0);
  int cur = 0;
  for (int kt = 0; kt < 8; ++kt) {
    if (kt < 7) {
      STAGE(cur ^ 1, kt + 1);
      asm volatile("s_waitcnt vmcnt(8)" ::: "memory");   // cur done, next in flight
    } else {
      asm volatile("s_waitcnt vmcnt(0)" ::: "memory");
    }
    __builtin_amdgcn_s_barrier();
    __builtin_amdgcn_sched_barrier(0);
    const unsigned short* Abuf = SWAP ? &sY[cur][0] : &sX[cur][0];
    const unsigned short* Bbuf = SWAP ? &sX[cur][0] : &sY[cur][0];
#pragma unroll
    for (int ks = 0; ks < 2; ++ks) {
      const int kk = ks * 32 + (lane >> 4) * 8;
      bf16x8 av[4], bv[4];
#pragma unroll
      for (int i = 0; i < 4; ++i) {
        int ra = wr * 64 + i * 16 + (lane & 15);
        av[i] = *(const bf16x8*)&Abuf[ra * 64 + (kk ^ ((ra & 7) << 3))];
        int rb = wc * 64 + i * 16 + (lane & 15);
        bv[i] = *(const bf16x8*)&Bbuf[rb * 64 + (kk ^ ((rb & 7) << 3))];
      }
#pragma unroll
      for (int i = 0; i < 4; ++i)
#pragma unroll
        for (int j = 0; j < 4; ++j)
          acc[i][j] = __builtin_amdgcn_mfma_f32_16x16x32_bf16(av[i], bv[j], acc[i][j], 0, 0, 0);
    }
    __builtin_amdgcn_s_barrier();
    cur ^= 1;
  }

  // ---- plain coalesced stores of the partial tile ----
  // C/D mapping (m89): col = lane&15 (B-row), row = (lane>>4)*4 + r (A-row)
  float* Og = Ppart + ((size_t)z * 8 + kz) * ((size_t)NN * DD);
  const int arow0 = wr * 64 + (lane >> 4) * 4;   // A-operand row base
  const int bcol0 = wc * 64 + (lane & 15);       // B-operand row (= out col)
#pragma unroll
  for (int i = 0; i < 4; ++i)
#pragma unroll
    for (int j = 0; j < 4; ++j)
#pragma unroll
      for (int r = 0; r < 4; ++r) {
        int a = arow0 + i * 16 + r;     // n for SWAP=0, m-local for SWAP=1
        int b = bcol0 + j * 16;         // m-local for SWAP=0, n for SWAP=1
        if (SWAP)  // [4096][128] m-major
          Og[(size_t)(bm * 128 + a) * DD + b] = acc[i][j][r];
        else       // [128][4096] n-major
          Og[(size_t)a * NN + bm * 128 + b] = acc[i][j][r];
      }
}

// ---------------------------------------------------------------------------
// reduceT: Tt[z][n][m] (bf16) = sum_kz P[z][kz][n][m]
// ---------------------------------------------------------------------------
__global__ __launch_bounds__(256) void reduceT_kernel(
    const float* __restrict__ P, unsigned short* __restrict__ Tt)
{
  size_t e = ((size_t)blockIdx.x * 256 + threadIdx.x) * 4;  // over [2][524288]
  size_t z = e >> 19, o = e & ((1ull << 19) - 1);
  const float* src = P + z * 8 * 524288 + o;
  float4 s = {0.f, 0.f, 0.f, 0.f};
#pragma unroll
  for (int kz = 0; kz < 8; ++kz) {
    float4 v = *(const float4*)&src[(size_t)kz * 524288];
    s.x += v.x; s.y += v.y; s.z += v.z; s.w += v.w;
  }
  ushort4 o4 = { f2bf(s.x), f2bf(s.y), f2bf(s.z), f2bf(s.w) };
  *(ushort4*)&Tt[e] = o4;
}

// ---------------------------------------------------------------------------
// reduce2: pre[z][m][n] = relu(sum_kz P[z][kz][m][n])
// ---------------------------------------------------------------------------
__global__ __launch_bounds__(256) void reduce2_kernel(
    const float* __restrict__ P, float* __restrict__ pre)
{
  size_t e = ((size_t)blockIdx.x * 256 + threadIdx.x) * 4;
  size_t z = e >> 19, o = e & ((1ull << 19) - 1);
  const float* src = P + z * 8 * 524288 + o;
  float4 s = {0.f, 0.f, 0.f, 0.f};
#pragma unroll
  for (int kz = 0; kz < 8; ++kz) {
    float4 v = *(const float4*)&src[(size_t)kz * 524288];
    s.x += v.x; s.y += v.y; s.z += v.z; s.w += v.w;
  }
  s.x = fmaxf(s.x, 0.f); s.y = fmaxf(s.y, 0.f);
  s.z = fmaxf(s.z, 0.f); s.w = fmaxf(s.w, 0.f);
  *(float4*)&pre[e] = s;
}

// ---------------------------------------------------------------------------
// tail: gather + domain mix + 2-layer MLP, one block = 16 batch rows.
// blockIdx.y: 0 = user path, 1 = item path. pre is POST-relu here.
// ---------------------------------------------------------------------------
#define FMA4(acc4, sc, wv) { (acc4).x += (sc) * (wv).x; (acc4).y += (sc) * (wv).y; \
                             (acc4).z += (sc) * (wv).z; (acc4).w += (sc) * (wv).w; }

__global__ __launch_bounds__(256) void tail_kernel(
    const float* __restrict__ preA, const float* __restrict__ preB,  // [4096][128]
    const float* __restrict__ rs, const float* __restrict__ cs,
    const float* __restrict__ attA, const float* __restrict__ attB,
    const int* __restrict__ u, const int* __restrict__ ii, const int* __restrict__ domp,
    const float* __restrict__ uW1, const float* __restrict__ ub1,
    const float* __restrict__ uW2, const float* __restrict__ ub2,
    const float* __restrict__ iW1, const float* __restrict__ ib1,
    const float* __restrict__ iW2, const float* __restrict__ ib2,
    float* __restrict__ out)
{
  __shared__ float sW[128 * 128];
  __shared__ float sX[16 * 128];
  __shared__ float sH[16 * 128];
  const int tid = threadIdx.x;
  const int path = blockIdx.y;
  const int b0 = blockIdx.x * 16;
  const int dom = domp[0];

  {  // gather + mix into sX
    int d = tid & 127, rr = tid >> 7;
#pragma unroll
    for (int it = 0; it < 8; ++it) {
      int rloc = it * 2 + rr;
      int b = b0 + rloc;
      float xv;
      if (path == 0) {
        int ub = u[b];
        float pA = preA[(size_t)ub * DD + d];
        float pB = preB[(size_t)ub * DD + d];
        float va = fmaxf(rs[ub] * cs[d], 0.f);
        float vb = fmaxf(rs[4096 + ub] * cs[128 + d], 0.f);
        float uA = pA + va, uB = pB + vb;
        float wgt = dom ? attB[(size_t)ub * DD + d] : attA[(size_t)ub * DD + d];
        xv = dom ? (uB * wgt + uA * (1.f - wgt)) : (uA * wgt + uB * (1.f - wgt));
      } else {
        int ib = ii[b];
        xv = (dom ? preB : preA)[(size_t)ib * DD + d];
      }
      sX[rloc * 128 + d] = xv;
    }
  }
  const float* W1 = path ? iW1 : uW1;
  const float* B1 = path ? ib1 : ub1;
  const float* W2 = path ? iW2 : uW2;
  const float* B2 = path ? ib2 : ub2;
#pragma unroll
  for (int it = 0; it < 16; ++it) {
    int idx = (it * 256 + tid) * 4;
    *(float4*)&sW[idx] = *(const float4*)&W1[idx];
  }
  __syncthreads();

  const int rl = tid >> 4, cg = (tid & 15) * 8;
  {  // layer 1 + relu -> sH
    float4 a0 = {0, 0, 0, 0}, a1 = {0, 0, 0, 0};
    const float* xr = &sX[rl * 128];
    for (int k = 0; k < 128; ++k) {
      float xk = xr[k];
      float4 w0 = *(const float4*)&sW[k * 128 + cg];
      float4 w1 = *(const float4*)&sW[k * 128 + cg + 4];
      FMA4(a0, xk, w0); FMA4(a1, xk, w1);
    }
    float4 c0 = *(const float4*)&B1[cg];
    float4 c1 = *(const float4*)&B1[cg + 4];
    a0.x = fmaxf(a0.x + c0.x, 0.f); a0.y = fmaxf(a0.y + c0.y, 0.f);
    a0.z = fmaxf(a0.z + c0.z, 0.f); a0.w = fmaxf(a0.w + c0.w, 0.f);
    a1.x = fmaxf(a1.x + c1.x, 0.f); a1.y = fmaxf(a1.y + c1.y, 0.f);
    a1.z = fmaxf(a1.z + c1.z, 0.f); a1.w = fmaxf(a1.w + c1.w, 0.f);
    *(float4*)&sH[rl * 128 + cg] = a0;
    *(float4*)&sH[rl * 128 + cg + 4] = a1;
  }
  __syncthreads();
#pragma unroll
  for (int it = 0; it < 16; ++it) {     // overwrite sW with W2
    int idx = (it * 256 + tid) * 4;
    *(float4*)&sW[idx] = *(const float4*)&W2[idx];
  }
  __syncthreads();
  {  // layer 2 -> out
    float4 a0 = {0, 0, 0, 0}, a1 = {0, 0, 0, 0};
    const float* hr = &sH[rl * 128];
    for (int k = 0; k < 128; ++k) {
      float hk = hr[k];
      float4 w0 = *(const float4*)&sW[k * 128 + cg];
      float4 w1 = *(const float4*)&sW[k * 128 + cg + 4];
      FMA4(a0, hk, w0); FMA4(a1, hk, w1);
    }
    float4 c0 = *(const float4*)&B2[cg];
    float4 c1 = *(const float4*)&B2[cg + 4];
    a0.x += c0.x; a0.y += c0.y; a0.z += c0.z; a0.w += c0.w;
    a1.x += c1.x; a1.y += c1.y; a1.z += c1.z; a1.w += c1.w;
    size_t row = (size_t)path * BATCH + b0 + rl;
    *(float4*)&out[row * DD + cg] = a0;
    *(float4*)&out[row * DD + cg + 4] = a1;
  }
}

// ---------------------------------------------------------------------------
extern "C" void kernel_launch(void* const* d_in, const int* in_sizes, int n_in,
                              void* d_out, int out_size, void* d_ws, size_t ws_size,
                              hipStream_t stream)
{
  const float* ratingA = (const float*)d_in[0];
  const float* ratingB = (const float*)d_in[1];
  const float* reviewA = (const float*)d_in[2];
  const float* reviewB = (const float*)d_in[3];
  const float* WgA = (const float*)d_in[4];
  const float* WgB = (const float*)d_in[5];
  const float* WrA = (const float*)d_in[6];
  const float* WrB = (const float*)d_in[7];
  const float* attA = (const float*)d_in[8];
  const float* attB = (const float*)d_in[9];
  const float* uW1 = (const float*)d_in[10];
  const float* ub1 = (const float*)d_in[11];
  const float* uW2 = (const float*)d_in[12];
  const float* ub2 = (const float*)d_in[13];
  const float* iW1 = (const float*)d_in[14];
  const float* ib1 = (const float*)d_in[15];
  const float* iW2 = (const float*)d_in[16];
  const float* ib2 = (const float*)d_in[17];
  const int* u   = (const int*)d_in[18];
  const int* ii  = (const int*)d_in[19];
  const int* dom = (const int*)d_in[20];
  float* out = (float*)d_out;

  const size_t ND = (size_t)NN * DD;            // 524288
  // workspace layout (~104 MB); Ppart shared between GEMM1 and GEMM2
  unsigned short* rating_bf = (unsigned short*)d_ws;             // 64 MB
  unsigned short* WgT = rating_bf + (size_t)2 * NN * NN;         //  2 MB
  unsigned short* Tt  = WgT + 2 * ND;                            //  2 MB
  float* Ppart = (float*)(Tt + 2 * ND);                          // 32 MB [2][8][524288]
  float* pre = Ppart + 16 * ND;                                  //  4 MB [2][4096][128]
  float* cs  = pre + 2 * ND;                                     //  1 KB
  float* rs  = cs + 256;                                         // 32 KB

  // zero only the colsum accumulator (everything else fully overwritten)
  hipMemsetAsync(cs, 0, 256 * sizeof(float), stream);

  prep_kernel<<<10880, 256, 0, stream>>>(ratingA, ratingB, reviewA, reviewB,
                                         WgA, WgB, WrA, WrB,
                                         rating_bf, WgT, rs, cs);

  // T'[d][i] partials = Wg^T @ rating^T slices
  gemm_tall<0><<<dim3(32, 8, 2), 256, 0, stream>>>(
      WgT, WgT + ND, rating_bf, rating_bf + (size_t)NN * NN, Ppart);
  reduceT_kernel<<<1024, 256, 0, stream>>>(Ppart, Tt);

  // pre[i][d] partials = rating @ T
  gemm_tall<1><<<dim3(32, 8, 2), 256, 0, stream>>>(
      Tt, Tt + ND, rating_bf, rating_bf + (size_t)NN * NN, Ppart);
  reduce2_kernel<<<1024, 256, 0, stream>>>(Ppart, pre);

  tail_kernel<<<dim3(256, 2), 256, 0, stream>>>(
      pre, pre + ND, rs, cs, attA, attB, u, ii, dom,
      uW1, ub1, uW2, ub2, iW1, ib1, iW2, ib2, out);
}